// Round 1
// baseline (936.945 us; speedup 1.0000x reference)
//
#include <hip/hip_runtime.h>
#include <stdint.h>

#define N_NODES 50000
#define D 128
#define NE 800000

typedef __bf16 bf16x8 __attribute__((ext_vector_type(8)));
typedef float floatx4 __attribute__((ext_vector_type(4)));

__device__ __forceinline__ unsigned short f2bf(float f) {
    unsigned u = __float_as_uint(f);
    u += 0x7fffu + ((u >> 16) & 1u);
    return (unsigned short)(u >> 16);
}
__device__ __forceinline__ float bf2f(unsigned short h) {
    return __uint_as_float(((unsigned)h) << 16);
}

// ---------------- CSR build ----------------
__global__ void k_hist(const int* __restrict__ dun, const int* __restrict__ dnu,
                       int* deg_n, int* deg_u) {
    int id = blockIdx.x * blockDim.x + threadIdx.x;
    if (id < NE) atomicAdd(&deg_n[dun[id]], 1);
    else if (id < 2 * NE) atomicAdd(&deg_u[dnu[id - NE]], 1);
}

__global__ void k_scan(const int* __restrict__ deg_n, const int* __restrict__ deg_u,
                       int* offs_n, int* offs_u) {
    const int* deg = blockIdx.x ? deg_u : deg_n;
    int* offs = blockIdx.x ? offs_u : offs_n;
    __shared__ int lds[1024];
    int t = threadIdx.x;
    const int CH = (N_NODES + 1023) / 1024;  // 49
    int base = t * CH;
    int end = min(base + CH, N_NODES);
    int s = 0;
    for (int i = base; i < end; ++i) s += deg[i];
    lds[t] = s;
    __syncthreads();
    for (int off = 1; off < 1024; off <<= 1) {
        int v = lds[t];
        int w = (t >= off) ? lds[t - off] : 0;
        __syncthreads();
        lds[t] = v + w;
        __syncthreads();
    }
    int run = lds[t] - s;  // exclusive base
    for (int i = base; i < end; ++i) { offs[i] = run; run += deg[i]; }
    if (t == 1023) offs[N_NODES] = lds[1023];
}

__global__ void k_scatter(const int* __restrict__ sun, const int* __restrict__ dun,
                          const int* __restrict__ snu, const int* __restrict__ dnu,
                          const int* __restrict__ offs_n, const int* __restrict__ offs_u,
                          int* cur_n, int* cur_u, int* srcs_n, int* srcs_u) {
    int id = blockIdx.x * blockDim.x + threadIdx.x;
    if (id < NE) {
        int d = dun[id];
        int p = offs_n[d] + atomicAdd(&cur_n[d], 1);
        srcs_n[p] = sun[id];
    } else if (id < 2 * NE) {
        int e = id - NE;
        int d = dnu[e];
        int p = offs_u[d] + atomicAdd(&cur_u[d], 1);
        srcs_u[p] = snu[e];
    }
}

// ------------- convert x/h fp32 -> bf16 into u3 (cols 128..255 = x, 384..511 = h) -------------
__global__ void k_conv_xh(const float* __restrict__ xu, const float* __restrict__ hu,
                          const float* __restrict__ xn, const float* __restrict__ hn,
                          unsigned short* u3_u, unsigned short* u3_n) {
    int id = blockIdx.x * blockDim.x + threadIdx.x;
    const int PER = N_NODES * (D / 4);  // 1,600,000
    int arr = id / PER;
    int rem = id - arr * PER;
    int row = rem >> 5;
    int c4 = rem & 31;
    const float* src;
    unsigned short* dst;
    int colbase;
    if (arr == 0)      { src = xu; dst = u3_u; colbase = 128; }
    else if (arr == 1) { src = hu; dst = u3_u; colbase = 384; }
    else if (arr == 2) { src = xn; dst = u3_n; colbase = 128; }
    else               { src = hn; dst = u3_n; colbase = 384; }
    float4 v = *(const float4*)(src + row * D + c4 * 4);
    ushort4 o;
    o.x = f2bf(v.x); o.y = f2bf(v.y); o.z = f2bf(v.z); o.w = f2bf(v.w);
    *(ushort4*)(dst + row * 512 + colbase + c4 * 4) = o;
}

// ------------- weights -> transposed stacked bf16 -------------
// per type t: [WzT 128x512][WrT 128x512][WcT 128x256][WhT 128x256], layout [n][k]
__global__ void k_conv_w(const float* __restrict__ Wl, const float* __restrict__ Wr,
                         unsigned short* wt) {
    int f = blockIdx.x * blockDim.x + threadIdx.x;
    if (f >= 2 * 196608) return;
    int t = f / 196608;
    int o = f - t * 196608;
    int g0, n, k;
    if (o < 65536)       { g0 = 0; n = o >> 9; k = o & 511; }
    else if (o < 131072) { o -= 65536;  g0 = 2; n = o >> 9; k = o & 511; }
    else if (o < 163840) { o -= 131072; g0 = 4; n = o >> 8; k = o & 255; }
    else                 { o -= 163840; g0 = 5; n = o >> 8; k = o & 255; }
    int seg = k >> 7;
    int kk = k & 127;
    int g = g0 + (seg >> 1);
    const float* W = (seg & 1) ? Wr : Wl;
    float v = W[((g * 2 + t) * 128 + kk) * 128 + n];
    wt[f] = f2bf(v);
}

// ------------- aggregation: mean of x,h rows per node (one wave per node) -------------
__global__ void k_agg2(const int* __restrict__ offs_n, const int* __restrict__ srcs_n,
                       const int* __restrict__ offs_u, const int* __restrict__ srcs_u,
                       const unsigned short* __restrict__ u3_n_ro,
                       const unsigned short* __restrict__ u3_u_ro,
                       unsigned short* u3_n, unsigned short* u3_u) {
    int dir = blockIdx.y;  // 0: news-side (gather user feats), 1: user-side (gather news)
    int node = blockIdx.x * 4 + (threadIdx.x >> 6);
    int lane = threadIdx.x & 63;
    const int* offs = dir ? offs_u : offs_n;
    const int* srcs = dir ? srcs_u : srcs_n;
    const unsigned short* src_feat = dir ? u3_n_ro : u3_u_ro;
    unsigned short* dst = dir ? u3_u : u3_n;
    int c0 = offs[node], c1 = offs[node + 1];
    float ax0 = 0.f, ax1 = 0.f, ah0 = 0.f, ah1 = 0.f;
    for (int e = c0; e < c1; ++e) {
        int s = srcs[e];
        const unsigned short* r = src_feat + (size_t)s * 512;
        ushort2 vx = *(const ushort2*)(r + 128 + lane * 2);
        ushort2 vh = *(const ushort2*)(r + 384 + lane * 2);
        ax0 += bf2f(vx.x); ax1 += bf2f(vx.y);
        ah0 += bf2f(vh.x); ah1 += bf2f(vh.y);
    }
    float inv = 1.f / (float)max(c1 - c0, 1);
    ushort2 ox, oh;
    ox.x = f2bf(ax0 * inv); ox.y = f2bf(ax1 * inv);
    oh.x = f2bf(ah0 * inv); oh.y = f2bf(ah1 * inv);
    *(ushort2*)(dst + (size_t)node * 512 + lane * 2) = ox;
    *(ushort2*)(dst + (size_t)node * 512 + 256 + lane * 2) = oh;
}

// ------------- aggregation of s = h*r (bf16 in u2 cols 128..255) -------------
__global__ void k_agg4(const int* __restrict__ offs_n, const int* __restrict__ srcs_n,
                       const int* __restrict__ offs_u, const int* __restrict__ srcs_u,
                       const unsigned short* __restrict__ u2_n_ro,
                       const unsigned short* __restrict__ u2_u_ro,
                       unsigned short* u2_n, unsigned short* u2_u) {
    int dir = blockIdx.y;
    int node = blockIdx.x * 4 + (threadIdx.x >> 6);
    int lane = threadIdx.x & 63;
    const int* offs = dir ? offs_u : offs_n;
    const int* srcs = dir ? srcs_u : srcs_n;
    const unsigned short* src_feat = dir ? u2_n_ro : u2_u_ro;
    unsigned short* dst = dir ? u2_u : u2_n;
    int c0 = offs[node], c1 = offs[node + 1];
    float a0 = 0.f, a1 = 0.f;
    for (int e = c0; e < c1; ++e) {
        int s = srcs[e];
        ushort2 v = *(const ushort2*)(src_feat + (size_t)s * 256 + 128 + lane * 2);
        a0 += bf2f(v.x); a1 += bf2f(v.y);
    }
    float inv = 1.f / (float)max(c1 - c0, 1);
    ushort2 o;
    o.x = f2bf(a0 * inv); o.y = f2bf(a1 * inv);
    *(ushort2*)(dst + (size_t)node * 256 + lane * 2) = o;
}

// ------------- phase 3: z, r, cx via MFMA; writes z, cx (bf16), s=h*r into u2 -------------
__global__ __launch_bounds__(256) void k_gates(
    const unsigned short* __restrict__ u3_n, const unsigned short* __restrict__ u3_u,
    const unsigned short* __restrict__ wt, const float* __restrict__ bias,
    const float* __restrict__ h_news, const float* __restrict__ h_user,
    unsigned short* z_n, unsigned short* z_u,
    unsigned short* cx_n, unsigned short* cx_u,
    unsigned short* u2_n, unsigned short* u2_u) {
    int t = blockIdx.y;  // 0 news, 1 user
    const unsigned short* u3 = t ? u3_u : u3_n;
    const float* h_in = t ? h_user : h_news;
    unsigned short* zb = t ? z_u : z_n;
    unsigned short* cb = t ? cx_u : cx_n;
    unsigned short* u2 = t ? u2_u : u2_n;
    const unsigned short* wbase = wt + t * 196608;

    __shared__ __align__(16) unsigned short lds[32 * 520];
    int row0 = blockIdx.x * 32;
    int tid = threadIdx.x;
    for (int i = tid; i < 2048; i += 256) {
        int r = i >> 6;
        int k8 = i & 63;
        uint4 v = make_uint4(0, 0, 0, 0);
        if (row0 + r < N_NODES) v = *(const uint4*)(u3 + (size_t)(row0 + r) * 512 + k8 * 8);
        *(uint4*)(&lds[r * 520 + k8 * 8]) = v;
    }
    __syncthreads();

    int lane = tid & 63;
    int w = tid >> 6;
    int l15 = lane & 15;
    int quad = lane >> 4;

    floatx4 zero = {0.f, 0.f, 0.f, 0.f};
    floatx4 accz[2][2], accr[2][2], accc[2][2];
    for (int i = 0; i < 2; ++i)
        for (int j = 0; j < 2; ++j) { accz[i][j] = zero; accr[i][j] = zero; accc[i][j] = zero; }

    const unsigned short* wz = wbase;
    const unsigned short* wr_ = wbase + 65536;
    const unsigned short* wc = wbase + 131072;

    for (int kt = 0; kt < 16; ++kt) {
        bf16x8 a0 = *(const bf16x8*)(&lds[l15 * 520 + kt * 32 + quad * 8]);
        bf16x8 a1 = *(const bf16x8*)(&lds[(16 + l15) * 520 + kt * 32 + quad * 8]);
        for (int nt = 0; nt < 2; ++nt) {
            int col = w * 32 + nt * 16 + l15;
            bf16x8 bz = *(const bf16x8*)(wz + col * 512 + kt * 32 + quad * 8);
            accz[0][nt] = __builtin_amdgcn_mfma_f32_16x16x32_bf16(a0, bz, accz[0][nt], 0, 0, 0);
            accz[1][nt] = __builtin_amdgcn_mfma_f32_16x16x32_bf16(a1, bz, accz[1][nt], 0, 0, 0);
            bf16x8 br = *(const bf16x8*)(wr_ + col * 512 + kt * 32 + quad * 8);
            accr[0][nt] = __builtin_amdgcn_mfma_f32_16x16x32_bf16(a0, br, accr[0][nt], 0, 0, 0);
            accr[1][nt] = __builtin_amdgcn_mfma_f32_16x16x32_bf16(a1, br, accr[1][nt], 0, 0, 0);
            if (kt < 8) {
                bf16x8 bc = *(const bf16x8*)(wc + col * 256 + kt * 32 + quad * 8);
                accc[0][nt] = __builtin_amdgcn_mfma_f32_16x16x32_bf16(a0, bc, accc[0][nt], 0, 0, 0);
                accc[1][nt] = __builtin_amdgcn_mfma_f32_16x16x32_bf16(a1, bc, accc[1][nt], 0, 0, 0);
            }
        }
    }

    for (int nt = 0; nt < 2; ++nt) {
        int col = w * 32 + nt * 16 + l15;
        float bz_ = bias[(0 * 2 + t) * 128 + col] + bias[(1 * 2 + t) * 128 + col];
        float br_ = bias[(2 * 2 + t) * 128 + col] + bias[(3 * 2 + t) * 128 + col];
        float bc_ = bias[(4 * 2 + t) * 128 + col];
        for (int mt = 0; mt < 2; ++mt) {
            for (int v = 0; v < 4; ++v) {
                int row = row0 + mt * 16 + quad * 4 + v;
                if (row < N_NODES) {
                    float zv = 1.f / (1.f + __expf(-(accz[mt][nt][v] + bz_)));
                    float rv = 1.f / (1.f + __expf(-(accr[mt][nt][v] + br_)));
                    float cv = accc[mt][nt][v] + bc_;
                    float hv = h_in[(size_t)row * 128 + col];
                    zb[(size_t)row * 128 + col] = f2bf(zv);
                    cb[(size_t)row * 128 + col] = f2bf(cv);
                    u2[(size_t)row * 256 + 128 + col] = f2bf(hv * rv);
                }
            }
        }
    }
}

// ------------- phase 5: ht = tanh(cx + [agg_s|s]@Wh + b5); h' = z*h + (1-z)*ht -------------
__global__ __launch_bounds__(256) void k_out(
    const unsigned short* __restrict__ u2_n, const unsigned short* __restrict__ u2_u,
    const unsigned short* __restrict__ wt, const float* __restrict__ bias,
    const unsigned short* __restrict__ z_n, const unsigned short* __restrict__ z_u,
    const unsigned short* __restrict__ cx_n, const unsigned short* __restrict__ cx_u,
    const float* __restrict__ h_news, const float* __restrict__ h_user, float* out) {
    int t = blockIdx.y;
    const unsigned short* u2 = t ? u2_u : u2_n;
    const unsigned short* zb = t ? z_u : z_n;
    const unsigned short* cb = t ? cx_u : cx_n;
    const float* h_in = t ? h_user : h_news;
    float* op = out + (t ? 0 : (size_t)N_NODES * D);  // output order: h_user first
    const unsigned short* wh = wt + t * 196608 + 163840;

    __shared__ __align__(16) unsigned short lds[32 * 264];
    int row0 = blockIdx.x * 32;
    int tid = threadIdx.x;
    for (int i = tid; i < 1024; i += 256) {
        int r = i >> 5;
        int k8 = i & 31;
        uint4 v = make_uint4(0, 0, 0, 0);
        if (row0 + r < N_NODES) v = *(const uint4*)(u2 + (size_t)(row0 + r) * 256 + k8 * 8);
        *(uint4*)(&lds[r * 264 + k8 * 8]) = v;
    }
    __syncthreads();

    int lane = tid & 63;
    int w = tid >> 6;
    int l15 = lane & 15;
    int quad = lane >> 4;
    floatx4 zero = {0.f, 0.f, 0.f, 0.f};
    floatx4 acc[2][2];
    for (int i = 0; i < 2; ++i) for (int j = 0; j < 2; ++j) acc[i][j] = zero;

    for (int kt = 0; kt < 8; ++kt) {
        bf16x8 a0 = *(const bf16x8*)(&lds[l15 * 264 + kt * 32 + quad * 8]);
        bf16x8 a1 = *(const bf16x8*)(&lds[(16 + l15) * 264 + kt * 32 + quad * 8]);
        for (int nt = 0; nt < 2; ++nt) {
            int col = w * 32 + nt * 16 + l15;
            bf16x8 b = *(const bf16x8*)(wh + col * 256 + kt * 32 + quad * 8);
            acc[0][nt] = __builtin_amdgcn_mfma_f32_16x16x32_bf16(a0, b, acc[0][nt], 0, 0, 0);
            acc[1][nt] = __builtin_amdgcn_mfma_f32_16x16x32_bf16(a1, b, acc[1][nt], 0, 0, 0);
        }
    }

    for (int nt = 0; nt < 2; ++nt) {
        int col = w * 32 + nt * 16 + l15;
        float bh_ = bias[(5 * 2 + t) * 128 + col];
        for (int mt = 0; mt < 2; ++mt) {
            for (int v = 0; v < 4; ++v) {
                int row = row0 + mt * 16 + quad * 4 + v;
                if (row < N_NODES) {
                    float x = bf2f(cb[(size_t)row * 128 + col]) + acc[mt][nt][v] + bh_;
                    x = fminf(fmaxf(x, -15.f), 15.f);
                    float e = __expf(2.f * x);
                    float ht = (e - 1.f) / (e + 1.f);
                    float zv = bf2f(zb[(size_t)row * 128 + col]);
                    float hv = h_in[(size_t)row * 128 + col];
                    op[(size_t)row * 128 + col] = zv * hv + (1.f - zv) * ht;
                }
            }
        }
    }
}

extern "C" void kernel_launch(void* const* d_in, const int* in_sizes, int n_in,
                              void* d_out, int out_size, void* d_ws, size_t ws_size,
                              hipStream_t stream) {
    const float* xu = (const float*)d_in[0];
    const float* xn = (const float*)d_in[1];
    const float* hu = (const float*)d_in[2];
    const float* hn = (const float*)d_in[3];
    const float* Wl = (const float*)d_in[4];
    const float* Wr = (const float*)d_in[5];
    const float* b  = (const float*)d_in[6];
    const int* sun = (const int*)d_in[7];
    const int* dun = (const int*)d_in[8];
    const int* snu = (const int*)d_in[9];
    const int* dnu = (const int*)d_in[10];
    float* out = (float*)d_out;

    char* ws = (char*)d_ws;
    size_t off = 0;
    auto alloc = [&](size_t bytes) -> void* {
        void* p = ws + off;
        off += (bytes + 255) & ~(size_t)255;
        return p;
    };
    unsigned short* wt = (unsigned short*)alloc((size_t)2 * 196608 * 2);
    int* zeros = (int*)alloc((size_t)4 * N_NODES * 4);  // deg_n, deg_u, cur_n, cur_u
    int* deg_n = zeros;
    int* deg_u = zeros + N_NODES;
    int* cur_n = zeros + 2 * N_NODES;
    int* cur_u = zeros + 3 * N_NODES;
    int* offs_n = (int*)alloc((size_t)(N_NODES + 1) * 4);
    int* offs_u = (int*)alloc((size_t)(N_NODES + 1) * 4);
    int* srcs_n = (int*)alloc((size_t)NE * 4);
    int* srcs_u = (int*)alloc((size_t)NE * 4);
    unsigned short* u3_n = (unsigned short*)alloc((size_t)N_NODES * 512 * 2);
    unsigned short* u3_u = (unsigned short*)alloc((size_t)N_NODES * 512 * 2);
    unsigned short* u2_n = (unsigned short*)alloc((size_t)N_NODES * 256 * 2);
    unsigned short* u2_u = (unsigned short*)alloc((size_t)N_NODES * 256 * 2);
    unsigned short* z_n  = (unsigned short*)alloc((size_t)N_NODES * 128 * 2);
    unsigned short* z_u  = (unsigned short*)alloc((size_t)N_NODES * 128 * 2);
    unsigned short* cx_n = (unsigned short*)alloc((size_t)N_NODES * 128 * 2);
    unsigned short* cx_u = (unsigned short*)alloc((size_t)N_NODES * 128 * 2);
    (void)in_sizes; (void)n_in; (void)out_size; (void)ws_size;

    hipMemsetAsync(zeros, 0, (size_t)4 * N_NODES * 4, stream);
    k_hist<<<(2 * NE + 255) / 256, 256, 0, stream>>>(dun, dnu, deg_n, deg_u);
    k_scan<<<2, 1024, 0, stream>>>(deg_n, deg_u, offs_n, offs_u);
    k_scatter<<<(2 * NE + 255) / 256, 256, 0, stream>>>(sun, dun, snu, dnu, offs_n, offs_u,
                                                        cur_n, cur_u, srcs_n, srcs_u);
    k_conv_xh<<<(4 * N_NODES * (D / 4)) / 256, 256, 0, stream>>>(xu, hu, xn, hn, u3_u, u3_n);
    k_conv_w<<<(2 * 196608 + 255) / 256, 256, 0, stream>>>(Wl, Wr, wt);
    k_agg2<<<dim3(N_NODES / 4, 2), 256, 0, stream>>>(offs_n, srcs_n, offs_u, srcs_u,
                                                     u3_n, u3_u, u3_n, u3_u);
    k_gates<<<dim3((N_NODES + 31) / 32, 2), 256, 0, stream>>>(u3_n, u3_u, wt, b, hn, hu,
                                                              z_n, z_u, cx_n, cx_u, u2_n, u2_u);
    k_agg4<<<dim3(N_NODES / 4, 2), 256, 0, stream>>>(offs_n, srcs_n, offs_u, srcs_u,
                                                     u2_n, u2_u, u2_n, u2_u);
    k_out<<<dim3((N_NODES + 31) / 32, 2), 256, 0, stream>>>(u2_n, u2_u, wt, b, z_n, z_u,
                                                            cx_n, cx_u, hn, hu, out);
}

// Round 2
// 786.968 us; speedup vs baseline: 1.1906x; 1.1906x over previous
//
#include <hip/hip_runtime.h>
#include <stdint.h>

#define N_NODES 50000
#define D 128
#define NE 800000

typedef __bf16 bf16x8 __attribute__((ext_vector_type(8)));
typedef float floatx4 __attribute__((ext_vector_type(4)));

__device__ __forceinline__ unsigned short f2bf(float f) {
    unsigned u = __float_as_uint(f);
    u += 0x7fffu + ((u >> 16) & 1u);
    return (unsigned short)(u >> 16);
}
__device__ __forceinline__ float bf2f(unsigned short h) {
    return __uint_as_float(((unsigned)h) << 16);
}

// ---------------- CSR build ----------------
__global__ void k_hist(const int* __restrict__ dun, const int* __restrict__ dnu,
                       int* deg_n, int* deg_u) {
    int id = blockIdx.x * blockDim.x + threadIdx.x;
    if (id < NE) atomicAdd(&deg_n[dun[id]], 1);
    else if (id < 2 * NE) atomicAdd(&deg_u[dnu[id - NE]], 1);
}

__global__ void k_scan(const int* __restrict__ deg_n, const int* __restrict__ deg_u,
                       int* offs_n, int* offs_u) {
    const int* deg = blockIdx.x ? deg_u : deg_n;
    int* offs = blockIdx.x ? offs_u : offs_n;
    __shared__ int lds[1024];
    int t = threadIdx.x;
    const int CH = (N_NODES + 1023) / 1024;  // 49
    int base = t * CH;
    int end = min(base + CH, N_NODES);
    int s = 0;
    for (int i = base; i < end; ++i) s += deg[i];
    lds[t] = s;
    __syncthreads();
    for (int off = 1; off < 1024; off <<= 1) {
        int v = lds[t];
        int w = (t >= off) ? lds[t - off] : 0;
        __syncthreads();
        lds[t] = v + w;
        __syncthreads();
    }
    int run = lds[t] - s;  // exclusive base
    for (int i = base; i < end; ++i) { offs[i] = run; run += deg[i]; }
    if (t == 1023) offs[N_NODES] = lds[1023];
}

__global__ void k_scatter(const int* __restrict__ sun, const int* __restrict__ dun,
                          const int* __restrict__ snu, const int* __restrict__ dnu,
                          const int* __restrict__ offs_n, const int* __restrict__ offs_u,
                          int* cur_n, int* cur_u, int* srcs_n, int* srcs_u) {
    int id = blockIdx.x * blockDim.x + threadIdx.x;
    if (id < NE) {
        int d = dun[id];
        int p = offs_n[d] + atomicAdd(&cur_n[d], 1);
        srcs_n[p] = sun[id];
    } else if (id < 2 * NE) {
        int e = id - NE;
        int d = dnu[e];
        int p = offs_u[d] + atomicAdd(&cur_u[d], 1);
        srcs_u[p] = snu[e];
    }
}

// ------------- convert x/h fp32 -> bf16 into u3 (cols 128..255 = x, 384..511 = h) -------------
__global__ void k_conv_xh(const float* __restrict__ xu, const float* __restrict__ hu,
                          const float* __restrict__ xn, const float* __restrict__ hn,
                          unsigned short* u3_u, unsigned short* u3_n) {
    int id = blockIdx.x * blockDim.x + threadIdx.x;
    const int PER = N_NODES * (D / 4);  // 1,600,000
    int arr = id / PER;
    int rem = id - arr * PER;
    int row = rem >> 5;
    int c4 = rem & 31;
    const float* src;
    unsigned short* dst;
    int colbase;
    if (arr == 0)      { src = xu; dst = u3_u; colbase = 128; }
    else if (arr == 1) { src = hu; dst = u3_u; colbase = 384; }
    else if (arr == 2) { src = xn; dst = u3_n; colbase = 128; }
    else               { src = hn; dst = u3_n; colbase = 384; }
    float4 v = *(const float4*)(src + row * D + c4 * 4);
    ushort4 o;
    o.x = f2bf(v.x); o.y = f2bf(v.y); o.z = f2bf(v.z); o.w = f2bf(v.w);
    *(ushort4*)(dst + row * 512 + colbase + c4 * 4) = o;
}

// ------------- weights -> transposed stacked bf16 -------------
// per type t: [WzT 128x512][WrT 128x512][WcT 128x256][WhT 128x256], layout [n][k]
__global__ void k_conv_w(const float* __restrict__ Wl, const float* __restrict__ Wr,
                         unsigned short* wt) {
    int f = blockIdx.x * blockDim.x + threadIdx.x;
    if (f >= 2 * 196608) return;
    int t = f / 196608;
    int o = f - t * 196608;
    int g0, n, k;
    if (o < 65536)       { g0 = 0; n = o >> 9; k = o & 511; }
    else if (o < 131072) { o -= 65536;  g0 = 2; n = o >> 9; k = o & 511; }
    else if (o < 163840) { o -= 131072; g0 = 4; n = o >> 8; k = o & 255; }
    else                 { o -= 163840; g0 = 5; n = o >> 8; k = o & 255; }
    int seg = k >> 7;
    int kk = k & 127;
    int g = g0 + (seg >> 1);
    const float* W = (seg & 1) ? Wr : Wl;
    float v = W[((g * 2 + t) * 128 + kk) * 128 + n];
    wt[f] = f2bf(v);
}

// ------------- agg2: mean of x,h rows per node; lanes 0..31 = x chunk, 32..63 = h chunk -------------
__global__ void k_agg2(const int* __restrict__ offs_n, const int* __restrict__ srcs_n,
                       const int* __restrict__ offs_u, const int* __restrict__ srcs_u,
                       const unsigned short* __restrict__ u3_n_ro,
                       const unsigned short* __restrict__ u3_u_ro,
                       unsigned short* u3_n, unsigned short* u3_u) {
    int dir = blockIdx.y;
    int node = blockIdx.x * 4 + (threadIdx.x >> 6);
    int lane = threadIdx.x & 63;
    const int* offs = dir ? offs_u : offs_n;
    const int* srcs = dir ? srcs_u : srcs_n;
    const unsigned short* src_feat = dir ? u3_n_ro : u3_u_ro;
    unsigned short* dst = dir ? u3_u : u3_n;
    int c0 = offs[node], c1 = offs[node + 1];
    int half = lane >> 5;       // 0: x, 1: h
    int chunk = lane & 31;      // which 4-elem (8B) chunk of the 128-col row
    int srcoff = (half ? 384 : 128) + chunk * 4;
    float a0 = 0.f, a1 = 0.f, a2 = 0.f, a3 = 0.f;
    int e = c0;
    for (; e + 3 < c1; e += 4) {
        int s0 = srcs[e], s1 = srcs[e + 1], s2 = srcs[e + 2], s3 = srcs[e + 3];
        ushort4 v0 = *(const ushort4*)(src_feat + (size_t)s0 * 512 + srcoff);
        ushort4 v1 = *(const ushort4*)(src_feat + (size_t)s1 * 512 + srcoff);
        ushort4 v2 = *(const ushort4*)(src_feat + (size_t)s2 * 512 + srcoff);
        ushort4 v3 = *(const ushort4*)(src_feat + (size_t)s3 * 512 + srcoff);
        a0 += bf2f(v0.x) + bf2f(v1.x) + bf2f(v2.x) + bf2f(v3.x);
        a1 += bf2f(v0.y) + bf2f(v1.y) + bf2f(v2.y) + bf2f(v3.y);
        a2 += bf2f(v0.z) + bf2f(v1.z) + bf2f(v2.z) + bf2f(v3.z);
        a3 += bf2f(v0.w) + bf2f(v1.w) + bf2f(v2.w) + bf2f(v3.w);
    }
    for (; e < c1; ++e) {
        int s = srcs[e];
        ushort4 v = *(const ushort4*)(src_feat + (size_t)s * 512 + srcoff);
        a0 += bf2f(v.x); a1 += bf2f(v.y); a2 += bf2f(v.z); a3 += bf2f(v.w);
    }
    float inv = 1.f / (float)max(c1 - c0, 1);
    ushort4 o;
    o.x = f2bf(a0 * inv); o.y = f2bf(a1 * inv); o.z = f2bf(a2 * inv); o.w = f2bf(a3 * inv);
    *(ushort4*)(dst + (size_t)node * 512 + (half ? 256 : 0) + chunk * 4) = o;
}

// ------------- agg4: mean of s rows; lane halves process alternating edges -------------
__global__ void k_agg4(const int* __restrict__ offs_n, const int* __restrict__ srcs_n,
                       const int* __restrict__ offs_u, const int* __restrict__ srcs_u,
                       const unsigned short* __restrict__ u2_n_ro,
                       const unsigned short* __restrict__ u2_u_ro,
                       unsigned short* u2_n, unsigned short* u2_u) {
    int dir = blockIdx.y;
    int node = blockIdx.x * 4 + (threadIdx.x >> 6);
    int lane = threadIdx.x & 63;
    const int* offs = dir ? offs_u : offs_n;
    const int* srcs = dir ? srcs_u : srcs_n;
    const unsigned short* src_feat = dir ? u2_n_ro : u2_u_ro;
    unsigned short* dst = dir ? u2_u : u2_n;
    int c0 = offs[node], c1 = offs[node + 1];
    int half = lane >> 5;
    int chunk = lane & 31;
    int srcoff = 128 + chunk * 4;
    float a0 = 0.f, a1 = 0.f, a2 = 0.f, a3 = 0.f;
    int e = c0 + half;
    for (; e + 2 < c1; e += 4) {
        int s0 = srcs[e], s1 = srcs[e + 2];
        ushort4 v0 = *(const ushort4*)(src_feat + (size_t)s0 * 256 + srcoff);
        ushort4 v1 = *(const ushort4*)(src_feat + (size_t)s1 * 256 + srcoff);
        a0 += bf2f(v0.x) + bf2f(v1.x);
        a1 += bf2f(v0.y) + bf2f(v1.y);
        a2 += bf2f(v0.z) + bf2f(v1.z);
        a3 += bf2f(v0.w) + bf2f(v1.w);
    }
    if (e < c1) {
        int s = srcs[e];
        ushort4 v = *(const ushort4*)(src_feat + (size_t)s * 256 + srcoff);
        a0 += bf2f(v.x); a1 += bf2f(v.y); a2 += bf2f(v.z); a3 += bf2f(v.w);
    }
    a0 += __shfl_xor(a0, 32);
    a1 += __shfl_xor(a1, 32);
    a2 += __shfl_xor(a2, 32);
    a3 += __shfl_xor(a3, 32);
    if (half == 0) {
        float inv = 1.f / (float)max(c1 - c0, 1);
        ushort4 o;
        o.x = f2bf(a0 * inv); o.y = f2bf(a1 * inv); o.z = f2bf(a2 * inv); o.w = f2bf(a3 * inv);
        *(ushort4*)(dst + (size_t)node * 256 + chunk * 4) = o;
    }
}

// ------------- phase 3: z, r, cx via MFMA; M=64 rows/block, no LDS -------------
__global__ __launch_bounds__(256) void k_gates(
    const unsigned short* __restrict__ u3_n, const unsigned short* __restrict__ u3_u,
    const unsigned short* __restrict__ wt, const float* __restrict__ bias,
    unsigned short* z_n, unsigned short* z_u,
    unsigned short* cx_n, unsigned short* cx_u,
    unsigned short* u2_n, unsigned short* u2_u) {
    int t = blockIdx.y;  // 0 news, 1 user
    const unsigned short* u3 = t ? u3_u : u3_n;
    unsigned short* zb = t ? z_u : z_n;
    unsigned short* cb = t ? cx_u : cx_n;
    unsigned short* u2 = t ? u2_u : u2_n;
    const unsigned short* wbase = wt + t * 196608;
    const unsigned short* wz = wbase;
    const unsigned short* wr_ = wbase + 65536;
    const unsigned short* wc = wbase + 131072;

    int row0 = blockIdx.x * 64;
    int tid = threadIdx.x;
    int lane = tid & 63;
    int w = tid >> 6;
    int l15 = lane & 15;
    int quad = lane >> 4;
    int cw = w * 32;

    floatx4 zero = {0.f, 0.f, 0.f, 0.f};
    floatx4 accz[4][2], accr[4][2], accc[4][2];
#pragma unroll
    for (int i = 0; i < 4; ++i)
#pragma unroll
        for (int j = 0; j < 2; ++j) { accz[i][j] = zero; accr[i][j] = zero; accc[i][j] = zero; }

    const unsigned short* arow[4];
#pragma unroll
    for (int rt = 0; rt < 4; ++rt) {
        int r = min(row0 + rt * 16 + l15, N_NODES - 1);
        arow[rt] = u3 + (size_t)r * 512;
    }

#pragma unroll
    for (int kt = 0; kt < 16; ++kt) {
        int ko = kt * 32 + quad * 8;
        bf16x8 a[4];
#pragma unroll
        for (int rt = 0; rt < 4; ++rt) a[rt] = *(const bf16x8*)(arow[rt] + ko);
#pragma unroll
        for (int ct = 0; ct < 2; ++ct) {
            int colg = cw + ct * 16 + l15;
            bf16x8 bz = *(const bf16x8*)(wz + colg * 512 + ko);
#pragma unroll
            for (int rt = 0; rt < 4; ++rt)
                accz[rt][ct] = __builtin_amdgcn_mfma_f32_16x16x32_bf16(a[rt], bz, accz[rt][ct], 0, 0, 0);
            bf16x8 br = *(const bf16x8*)(wr_ + colg * 512 + ko);
#pragma unroll
            for (int rt = 0; rt < 4; ++rt)
                accr[rt][ct] = __builtin_amdgcn_mfma_f32_16x16x32_bf16(a[rt], br, accr[rt][ct], 0, 0, 0);
            if (kt < 8) {
                bf16x8 bc = *(const bf16x8*)(wc + colg * 256 + ko);
#pragma unroll
                for (int rt = 0; rt < 4; ++rt)
                    accc[rt][ct] = __builtin_amdgcn_mfma_f32_16x16x32_bf16(a[rt], bc, accc[rt][ct], 0, 0, 0);
            }
        }
    }

#pragma unroll
    for (int ct = 0; ct < 2; ++ct) {
        int col = cw + ct * 16 + l15;
        float bz_ = bias[(0 * 2 + t) * 128 + col] + bias[(1 * 2 + t) * 128 + col];
        float br_ = bias[(2 * 2 + t) * 128 + col] + bias[(3 * 2 + t) * 128 + col];
        float bc_ = bias[(4 * 2 + t) * 128 + col];
#pragma unroll
        for (int rt = 0; rt < 4; ++rt) {
#pragma unroll
            for (int v = 0; v < 4; ++v) {
                int row = row0 + rt * 16 + quad * 4 + v;
                if (row < N_NODES) {
                    float zv = 1.f / (1.f + __expf(-(accz[rt][ct][v] + bz_)));
                    float rv = 1.f / (1.f + __expf(-(accr[rt][ct][v] + br_)));
                    float cv = accc[rt][ct][v] + bc_;
                    float hv = bf2f(u3[(size_t)row * 512 + 384 + col]);
                    zb[(size_t)row * 128 + col] = f2bf(zv);
                    cb[(size_t)row * 128 + col] = f2bf(cv);
                    u2[(size_t)row * 256 + 128 + col] = f2bf(hv * rv);
                }
            }
        }
    }
}

// ------------- phase 5: ht = tanh(cx + [agg_s|s]@Wh + b5); h' = z*h + (1-z)*ht -------------
__global__ __launch_bounds__(256) void k_out(
    const unsigned short* __restrict__ u2_n, const unsigned short* __restrict__ u2_u,
    const unsigned short* __restrict__ u3_n, const unsigned short* __restrict__ u3_u,
    const unsigned short* __restrict__ wt, const float* __restrict__ bias,
    const unsigned short* __restrict__ z_n, const unsigned short* __restrict__ z_u,
    const unsigned short* __restrict__ cx_n, const unsigned short* __restrict__ cx_u,
    float* out) {
    int t = blockIdx.y;
    const unsigned short* u2 = t ? u2_u : u2_n;
    const unsigned short* u3 = t ? u3_u : u3_n;
    const unsigned short* zb = t ? z_u : z_n;
    const unsigned short* cb = t ? cx_u : cx_n;
    float* op = out + (t ? 0 : (size_t)N_NODES * D);  // output order: h_user first
    const unsigned short* wh = wt + t * 196608 + 163840;

    int row0 = blockIdx.x * 64;
    int tid = threadIdx.x;
    int lane = tid & 63;
    int w = tid >> 6;
    int l15 = lane & 15;
    int quad = lane >> 4;
    int cw = w * 32;

    floatx4 zero = {0.f, 0.f, 0.f, 0.f};
    floatx4 acc[4][2];
#pragma unroll
    for (int i = 0; i < 4; ++i)
#pragma unroll
        for (int j = 0; j < 2; ++j) acc[i][j] = zero;

    const unsigned short* arow[4];
#pragma unroll
    for (int rt = 0; rt < 4; ++rt) {
        int r = min(row0 + rt * 16 + l15, N_NODES - 1);
        arow[rt] = u2 + (size_t)r * 256;
    }

#pragma unroll
    for (int kt = 0; kt < 8; ++kt) {
        int ko = kt * 32 + quad * 8;
        bf16x8 a[4];
#pragma unroll
        for (int rt = 0; rt < 4; ++rt) a[rt] = *(const bf16x8*)(arow[rt] + ko);
#pragma unroll
        for (int ct = 0; ct < 2; ++ct) {
            int colg = cw + ct * 16 + l15;
            bf16x8 b = *(const bf16x8*)(wh + colg * 256 + ko);
#pragma unroll
            for (int rt = 0; rt < 4; ++rt)
                acc[rt][ct] = __builtin_amdgcn_mfma_f32_16x16x32_bf16(a[rt], b, acc[rt][ct], 0, 0, 0);
        }
    }

#pragma unroll
    for (int ct = 0; ct < 2; ++ct) {
        int col = cw + ct * 16 + l15;
        float bh_ = bias[(5 * 2 + t) * 128 + col];
#pragma unroll
        for (int rt = 0; rt < 4; ++rt) {
#pragma unroll
            for (int v = 0; v < 4; ++v) {
                int row = row0 + rt * 16 + quad * 4 + v;
                if (row < N_NODES) {
                    float x = bf2f(cb[(size_t)row * 128 + col]) + acc[rt][ct][v] + bh_;
                    x = fminf(fmaxf(x, -15.f), 15.f);
                    float e = __expf(2.f * x);
                    float ht = (e - 1.f) / (e + 1.f);
                    float zv = bf2f(zb[(size_t)row * 128 + col]);
                    float hv = bf2f(u3[(size_t)row * 512 + 384 + col]);
                    op[(size_t)row * 128 + col] = zv * hv + (1.f - zv) * ht;
                }
            }
        }
    }
}

extern "C" void kernel_launch(void* const* d_in, const int* in_sizes, int n_in,
                              void* d_out, int out_size, void* d_ws, size_t ws_size,
                              hipStream_t stream) {
    const float* xu = (const float*)d_in[0];
    const float* xn = (const float*)d_in[1];
    const float* hu = (const float*)d_in[2];
    const float* hn = (const float*)d_in[3];
    const float* Wl = (const float*)d_in[4];
    const float* Wr = (const float*)d_in[5];
    const float* b  = (const float*)d_in[6];
    const int* sun = (const int*)d_in[7];
    const int* dun = (const int*)d_in[8];
    const int* snu = (const int*)d_in[9];
    const int* dnu = (const int*)d_in[10];
    float* out = (float*)d_out;

    char* ws = (char*)d_ws;
    size_t off = 0;
    auto alloc = [&](size_t bytes) -> void* {
        void* p = ws + off;
        off += (bytes + 255) & ~(size_t)255;
        return p;
    };
    unsigned short* wt = (unsigned short*)alloc((size_t)2 * 196608 * 2);
    int* zeros = (int*)alloc((size_t)4 * N_NODES * 4);  // deg_n, deg_u, cur_n, cur_u
    int* deg_n = zeros;
    int* deg_u = zeros + N_NODES;
    int* cur_n = zeros + 2 * N_NODES;
    int* cur_u = zeros + 3 * N_NODES;
    int* offs_n = (int*)alloc((size_t)(N_NODES + 1) * 4);
    int* offs_u = (int*)alloc((size_t)(N_NODES + 1) * 4);
    int* srcs_n = (int*)alloc((size_t)NE * 4);
    int* srcs_u = (int*)alloc((size_t)NE * 4);
    unsigned short* u3_n = (unsigned short*)alloc((size_t)N_NODES * 512 * 2);
    unsigned short* u3_u = (unsigned short*)alloc((size_t)N_NODES * 512 * 2);
    unsigned short* u2_n = (unsigned short*)alloc((size_t)N_NODES * 256 * 2);
    unsigned short* u2_u = (unsigned short*)alloc((size_t)N_NODES * 256 * 2);
    unsigned short* z_n  = (unsigned short*)alloc((size_t)N_NODES * 128 * 2);
    unsigned short* z_u  = (unsigned short*)alloc((size_t)N_NODES * 128 * 2);
    unsigned short* cx_n = (unsigned short*)alloc((size_t)N_NODES * 128 * 2);
    unsigned short* cx_u = (unsigned short*)alloc((size_t)N_NODES * 128 * 2);
    (void)in_sizes; (void)n_in; (void)out_size; (void)ws_size;

    hipMemsetAsync(zeros, 0, (size_t)4 * N_NODES * 4, stream);
    k_hist<<<(2 * NE + 255) / 256, 256, 0, stream>>>(dun, dnu, deg_n, deg_u);
    k_scan<<<2, 1024, 0, stream>>>(deg_n, deg_u, offs_n, offs_u);
    k_scatter<<<(2 * NE + 255) / 256, 256, 0, stream>>>(sun, dun, snu, dnu, offs_n, offs_u,
                                                        cur_n, cur_u, srcs_n, srcs_u);
    k_conv_xh<<<(4 * N_NODES * (D / 4)) / 256, 256, 0, stream>>>(xu, hu, xn, hn, u3_u, u3_n);
    k_conv_w<<<(2 * 196608 + 255) / 256, 256, 0, stream>>>(Wl, Wr, wt);
    k_agg2<<<dim3(N_NODES / 4, 2), 256, 0, stream>>>(offs_n, srcs_n, offs_u, srcs_u,
                                                     u3_n, u3_u, u3_n, u3_u);
    k_gates<<<dim3((N_NODES + 63) / 64, 2), 256, 0, stream>>>(u3_n, u3_u, wt, b,
                                                              z_n, z_u, cx_n, cx_u, u2_n, u2_u);
    k_agg4<<<dim3(N_NODES / 4, 2), 256, 0, stream>>>(offs_n, srcs_n, offs_u, srcs_u,
                                                     u2_n, u2_u, u2_n, u2_u);
    k_out<<<dim3((N_NODES + 63) / 64, 2), 256, 0, stream>>>(u2_n, u2_u, u3_n, u3_u, wt, b,
                                                            z_n, z_u, cx_n, cx_u, out);
}